// Round 6
// baseline (285.466 us; speedup 1.0000x reference)
//
#include <hip/hip_runtime.h>

// GaussianSplatting preprocess:
//   out = concat(positions [N,3], cov [N,3,3], alphas [N], sh [N,4]) flat f32
//   cov = R (S S^T) R^T = (R S)(R S)^T
//   sh  = [SH_C0, c1*SH_C1, c0*SH_C1, c2*SH_C1]
//
// v5b = v4b (LDS-coalesced, compulsory traffic: FETCH 95.4 + WRITE 129.7 MB)
//       + NON-TEMPORAL stores via clang ext_vector_type(4) (R5 fix:
//       __builtin_nontemporal_store rejects HIP_vector_type float4*;
//       native vector type accepted, same 16B layout -> dwordx4 nt).
// Theory (R4): with perfect coalescing and exactly-compulsory traffic the
// kernel still runs 2.4 TB/s. Output writes allocate in the 256 MB MALL and
// evict the 200 MB input each iteration (FETCH ~= input - resident share).
// Full-line nt stores should no-allocate -> input L3-resident -> FETCH drops.
// Falsification: WRITE inflates -> merge story wrong; FETCH unchanged ->
// nt doesn't control MALL allocation (lever dead -> platform ceiling).

#define SH_C0 0.282095f
#define SH_C1 0.488603f
#define BLK 256

typedef float f32x4 __attribute__((ext_vector_type(4)));

__device__ __forceinline__ void nt_store4(float4* p, float4 v) {
    f32x4 w = { v.x, v.y, v.z, v.w };
    __builtin_nontemporal_store(w, (f32x4*)p);
}

__global__ __launch_bounds__(BLK) void gs_kernel(
    const float* __restrict__ pos,
    const float* __restrict__ col,
    const float* __restrict__ alp,
    const float* __restrict__ Rm,
    const float* __restrict__ Sm,
    float* __restrict__ out_pos,   // [n*3]
    float* __restrict__ out_cov,   // [n*9]
    float* __restrict__ out_alp,   // [n]
    float* __restrict__ out_sh,    // [n*4]
    int n)
{
    // 256 points/block: R,S,cov = 576 float4 (9 KB) each, col = 192 float4 (3 KB)
    __shared__ float4 ldsR4[576];
    __shared__ float4 ldsS4[576];
    __shared__ float4 ldsC4[576];   // cov out-staging
    __shared__ float4 ldsCol4[192];

    const int t = threadIdx.x;
    const int base = blockIdx.x * BLK;  // first point of this block

    if (base + BLK <= n) {
        // ---------------- full-block fast path ----------------
        const float4* R4 = (const float4*)(Rm  + (size_t)base * 9);
        const float4* S4 = (const float4*)(Sm  + (size_t)base * 9);
        const float4* C4 = (const float4*)(col + (size_t)base * 3);
        const float4* P4 = (const float4*)(pos + (size_t)base * 3);
        const float4* A4 = (const float4*)(alp + (size_t)base);
        float4* OP4 = (float4*)(out_pos + (size_t)base * 3);
        float4* OA4 = (float4*)(out_alp + (size_t)base);
        float4* OS4 = (float4*)(out_sh  + (size_t)base * 4);
        float4* OC4 = (float4*)(out_cov + (size_t)base * 9);

        // stage inputs (each wave64 float4 instr = 1024 B = 8 full lines)
        ldsR4[t]       = R4[t];
        ldsR4[t + 256] = R4[t + 256];
        ldsS4[t]       = S4[t];
        ldsS4[t + 256] = S4[t + 256];
        if (t < 64) {
            ldsR4[t + 512] = R4[t + 512];
            ldsS4[t + 512] = S4[t + 512];
            nt_store4(&OA4[t], A4[t]);           // alphas passthrough
        }
        if (t < 192) {
            ldsCol4[t] = C4[t];
            nt_store4(&OP4[t], P4[t]);           // positions passthrough
        }

        __syncthreads();

        // per-thread compute from LDS (stride-9 floats -> 2-way bank alias = free)
        const float* rf = (const float*)ldsR4 + t * 9;
        const float* sf = (const float*)ldsS4 + t * 9;
        float r[9], s[9];
#pragma unroll
        for (int k = 0; k < 9; ++k) r[k] = rf[k];
#pragma unroll
        for (int k = 0; k < 9; ++k) s[k] = sf[k];

        float tm[9];  // T = R @ S
#pragma unroll
        for (int a = 0; a < 3; ++a)
#pragma unroll
            for (int b = 0; b < 3; ++b)
                tm[3 * a + b] = r[3 * a + 0] * s[0 + b]
                              + r[3 * a + 1] * s[3 + b]
                              + r[3 * a + 2] * s[6 + b];

        float* cf = (float*)ldsC4 + t * 9;
#pragma unroll
        for (int a = 0; a < 3; ++a)
#pragma unroll
            for (int b = 0; b < 3; ++b)
                cf[3 * a + b] = tm[3 * a + 0] * tm[3 * b + 0]
                              + tm[3 * a + 1] * tm[3 * b + 1]
                              + tm[3 * a + 2] * tm[3 * b + 2];

        // sh: one float4 per point -> naturally coalesced direct nt store
        const float* cc = (const float*)ldsCol4 + t * 3;
        nt_store4(&OS4[t],
                  make_float4(SH_C0, cc[1] * SH_C1, cc[0] * SH_C1, cc[2] * SH_C1));

        __syncthreads();

        // cov: cooperative coalesced float4 nt store
        nt_store4(&OC4[t],       ldsC4[t]);
        nt_store4(&OC4[t + 256], ldsC4[t + 256]);
        if (t < 64) nt_store4(&OC4[t + 512], ldsC4[t + 512]);
    } else {
        // ---------------- guarded scalar tail ----------------
        int i = base + t;
        if (i >= n) return;

        out_pos[3 * i + 0] = pos[3 * i + 0];
        out_pos[3 * i + 1] = pos[3 * i + 1];
        out_pos[3 * i + 2] = pos[3 * i + 2];
        out_alp[i] = alp[i];

        float c0 = col[3 * i + 0];
        float c1 = col[3 * i + 1];
        float c2 = col[3 * i + 2];
        out_sh[4 * i + 0] = SH_C0;
        out_sh[4 * i + 1] = c1 * SH_C1;
        out_sh[4 * i + 2] = c0 * SH_C1;
        out_sh[4 * i + 3] = c2 * SH_C1;

        float r[9], s[9];
#pragma unroll
        for (int k = 0; k < 9; ++k) r[k] = Rm[9 * i + k];
#pragma unroll
        for (int k = 0; k < 9; ++k) s[k] = Sm[9 * i + k];

        float tm[9];
#pragma unroll
        for (int a = 0; a < 3; ++a)
#pragma unroll
            for (int b = 0; b < 3; ++b)
                tm[3 * a + b] = r[3 * a + 0] * s[0 + b]
                              + r[3 * a + 1] * s[3 + b]
                              + r[3 * a + 2] * s[6 + b];

#pragma unroll
        for (int a = 0; a < 3; ++a)
#pragma unroll
            for (int b = 0; b < 3; ++b)
                out_cov[9 * i + 3 * a + b] = tm[3 * a + 0] * tm[3 * b + 0]
                                           + tm[3 * a + 1] * tm[3 * b + 1]
                                           + tm[3 * a + 2] * tm[3 * b + 2];
    }
}

extern "C" void kernel_launch(void* const* d_in, const int* in_sizes, int n_in,
                              void* d_out, int out_size, void* d_ws, size_t ws_size,
                              hipStream_t stream) {
    const float* pos = (const float*)d_in[0];  // [N,3]
    const float* col = (const float*)d_in[1];  // [N,3]
    const float* alp = (const float*)d_in[2];  // [N]
    const float* Rm  = (const float*)d_in[3];  // [N,3,3]
    const float* Sm  = (const float*)d_in[4];  // [N,3,3]

    int n = in_sizes[0] / 3;

    float* out = (float*)d_out;
    float* out_pos = out;             // n*3
    float* out_cov = out + 3 * n;     // n*9
    float* out_alp = out + 12 * n;    // n
    float* out_sh  = out + 13 * n;    // n*4

    int block = BLK;
    int grid = (n + block - 1) / block;
    gs_kernel<<<grid, block, 0, stream>>>(pos, col, alp, Rm, Sm,
                                          out_pos, out_cov, out_alp, out_sh, n);
}

// Round 7
// 280.417 us; speedup vs baseline: 1.0180x; 1.0180x over previous
//
#include <hip/hip_runtime.h>

// GaussianSplatting preprocess:
//   out = concat(positions [N,3], cov [N,3,3], alphas [N], sh [N,4]) flat f32
//   cov = R (S S^T) R^T = (R S)(R S)^T
//   sh  = [SH_C0, c1*SH_C1, c0*SH_C1, c2*SH_C1]
//
// v6: PHASE-ORDERED grid-stride. Ledger: v1 scalar (95us), v4 vector (137),
// v4b LDS-coalesced (97.5), v5b +nt (105) — all at 2.40-2.48 TB/s with
// compulsory 236 MB hbm_bytes; per-CU resources <5% busy. Last standing
// theory: 9 concurrent address streams (5 in + 4 out from every CU at once)
// thrash DRAM page locality / controller queues; the 6.3 TB/s copy ubench
// runs 2 streams. Fix: the four outputs are independent -> process as
// sequential PHASES (pos-copy | alp-copy | col->sh | R,S->cov), each a
// 2-3-stream copy-like pattern. 2048 grid-stride blocks stay statistically
// phase-aligned; no syncs needed (no cross-region deps).
// Falsification: if BW stays ~2.45 TB/s, the plateau is the platform
// ceiling for this op (scalar/vector/LDS/nt/topology all refuted).

#define SH_C0 0.282095f
#define SH_C1 0.488603f
#define BLK 256
#define GRID 2048

__global__ __launch_bounds__(BLK) void gs_kernel(
    const float* __restrict__ pos,
    const float* __restrict__ col,
    const float* __restrict__ alp,
    const float* __restrict__ Rm,
    const float* __restrict__ Sm,
    float* __restrict__ out_pos,   // [n*3]
    float* __restrict__ out_cov,   // [n*9]
    float* __restrict__ out_alp,   // [n]
    float* __restrict__ out_sh,    // [n*4]
    int n)
{
    const int T = gridDim.x * blockDim.x;
    const int g = blockIdx.x * blockDim.x + threadIdx.x;

    // ---- Phase A: positions passthrough (pure 2-stream float4 copy) ----
    {
        const int nf = 3 * n;
        const int n4 = nf >> 2;
        const float4* src = (const float4*)pos;
        float4* dst = (float4*)out_pos;
        for (int u = g; u < n4; u += T) dst[u] = src[u];
        for (int u = (n4 << 2) + g; u < nf; u += T) out_pos[u] = pos[u];
    }

    // ---- Phase B: alphas passthrough (pure 2-stream float4 copy) ----
    {
        const int n4 = n >> 2;
        const float4* src = (const float4*)alp;
        float4* dst = (float4*)out_alp;
        for (int u = g; u < n4; u += T) dst[u] = src[u];
        for (int u = (n4 << 2) + g; u < n; u += T) out_alp[u] = alp[u];
    }

    // ---- Phase C: col -> sh (2 streams; sh is a natural float4/point) ----
    {
        float4* sh4 = (float4*)out_sh;
        for (int i = g; i < n; i += T) {
            float c0 = col[3 * i + 0];
            float c1 = col[3 * i + 1];
            float c2 = col[3 * i + 2];
            sh4[i] = make_float4(SH_C0, c1 * SH_C1, c0 * SH_C1, c2 * SH_C1);
        }
    }

    // ---- Phase D: R,S -> cov (3 streams; 65% of all bytes) ----
    for (int i = g; i < n; i += T) {
        float r[9], s[9];
#pragma unroll
        for (int k = 0; k < 9; ++k) r[k] = Rm[9 * i + k];
#pragma unroll
        for (int k = 0; k < 9; ++k) s[k] = Sm[9 * i + k];

        float t[9];  // T = R @ S
#pragma unroll
        for (int a = 0; a < 3; ++a)
#pragma unroll
            for (int b = 0; b < 3; ++b)
                t[3 * a + b] = r[3 * a + 0] * s[0 + b]
                             + r[3 * a + 1] * s[3 + b]
                             + r[3 * a + 2] * s[6 + b];

#pragma unroll
        for (int a = 0; a < 3; ++a)
#pragma unroll
            for (int b = 0; b < 3; ++b)
                out_cov[9 * i + 3 * a + b] = t[3 * a + 0] * t[3 * b + 0]
                                           + t[3 * a + 1] * t[3 * b + 1]
                                           + t[3 * a + 2] * t[3 * b + 2];
    }
}

extern "C" void kernel_launch(void* const* d_in, const int* in_sizes, int n_in,
                              void* d_out, int out_size, void* d_ws, size_t ws_size,
                              hipStream_t stream) {
    const float* pos = (const float*)d_in[0];  // [N,3]
    const float* col = (const float*)d_in[1];  // [N,3]
    const float* alp = (const float*)d_in[2];  // [N]
    const float* Rm  = (const float*)d_in[3];  // [N,3,3]
    const float* Sm  = (const float*)d_in[4];  // [N,3,3]

    int n = in_sizes[0] / 3;

    float* out = (float*)d_out;
    float* out_pos = out;             // n*3
    float* out_cov = out + 3 * n;     // n*9
    float* out_alp = out + 12 * n;    // n
    float* out_sh  = out + 13 * n;    // n*4

    gs_kernel<<<GRID, BLK, 0, stream>>>(pos, col, alp, Rm, Sm,
                                        out_pos, out_cov, out_alp, out_sh, n);
}